// Round 14
// baseline (413.984 us; speedup 1.0000x reference)
//
#include <hip/hip_runtime.h>
#include <hip/hip_bf16.h>

namespace {

constexpr int B  = 2;
constexpr int C  = 64;
constexpr int CQ = 8;
constexpr int H  = 270;
constexpr int W  = 480;
constexpr int HW = H * W;
constexpr float INVH2 = 2.0f / (270.0f * 270.0f);  // dw_h = exp(-d^2 * INVH2)
constexpr float INVW2 = 2.0f / (480.0f * 480.0f);
constexpr float LOG2E = 1.44269504088896340736f;

#if __has_builtin(__builtin_amdgcn_exp2f)
#define EXP2F(x) __builtin_amdgcn_exp2f(x)
#else
#define EXP2F(x) exp2f(x)
#endif

typedef __attribute__((ext_vector_type(4))) float f32x4;
typedef __attribute__((ext_vector_type(8))) short short8;
typedef __attribute__((ext_vector_type(4))) unsigned int uint4v;

__device__ __forceinline__ float bits2f(unsigned short u) {
  union { unsigned int i; float f; } cv;
  cv.i = ((unsigned int)u) << 16;
  return cv.f;
}

__device__ __forceinline__ unsigned short f2bf(float f) {
  union { __hip_bfloat16 b; unsigned short u; } cv;
  cv.b = __float2bfloat16(f);
  return cv.u;
}

__device__ __forceinline__ unsigned int pack2(float a, float b) {
  return ((unsigned int)f2bf(b) << 16) | (unsigned int)f2bf(a);
}

__device__ __forceinline__ short8 pack_p(const float p0[4], const float p1[4]) {
  uint4v pw;
  pw[0] = pack2(p0[0], p0[1]);
  pw[1] = pack2(p0[2], p0[3]);
  pw[2] = pack2(p1[0], p1[1]);
  pw[3] = pack2(p1[2], p1[3]);
  return __builtin_bit_cast(short8, pw);
}

// V-row permutation inside each 32-row K-step so that the swapped-QK P layout
// (lane quad q holds g = 4q+rr from E0 and 16+4q+rr from E1) feeds the PV
// A-fragment (k-slot q*8+j) with NO cross-lane data movement:
//   u < 16: slot = 8*(u>>2) + (u&3);  u >= 16: slot = 8*((u-16)>>2) + 4 + (u&3)

// ---------------------------------------------------------------------------
// K1: q/k/v 1x1 projections, two adjacent pixels per thread. NO LDS: weight
// addresses are wave-uniform, so direct global reads compile to s_load into
// SGPRs (scalar pipe + scalar cache) and v_fma takes the SGPR operand. This
// frees the vector-LDS pipe, which was co-saturated with VALU (80
// ds_read_b128 vs 640 FMA per c-step) and capped VALUBusy at ~50%.
// ---------------------------------------------------------------------------
__global__ __launch_bounds__(256, 1)
void k_qkv(const float* __restrict__ x,
           const float* __restrict__ Wq, const float* __restrict__ bq,
           const float* __restrict__ Wk, const float* __restrict__ bk,
           const float* __restrict__ Wv, const float* __restrict__ bv,
           unsigned short* __restrict__ qwp, unsigned short* __restrict__ kwp,
           unsigned short* __restrict__ qhp, unsigned short* __restrict__ khp,
           unsigned short* __restrict__ v, unsigned short* __restrict__ vt) {
  const int tid = threadIdx.x;
  const int pix0 = (blockIdx.x * 256 + tid) * 2;
  if (pix0 >= B * HW) return;
  const int b = pix0 / HW;
  const int r = pix0 - b * HW;   // even; pixels r and r+1 share b and h
  const int h = r / W;
  const int w = r - h * W;       // even; w+1 < W

  float qa0[CQ], qa1[CQ], ka0[CQ], ka1[CQ], va0[C], va1[C];
#pragma unroll
  for (int o = 0; o < CQ; ++o) {
    qa0[o] = bq[o]; qa1[o] = bq[o];
    ka0[o] = bk[o]; ka1[o] = bk[o];
  }
#pragma unroll
  for (int o = 0; o < C; ++o) { va0[o] = bv[o]; va1[o] = bv[o]; }

  const float* xp = x + (size_t)b * C * HW + r;
  for (int c = 0; c < C; c += 4) {
    const float2 x0 = *(const float2*)(xp + (size_t)(c + 0) * HW);
    const float2 x1 = *(const float2*)(xp + (size_t)(c + 1) * HW);
    const float2 x2 = *(const float2*)(xp + (size_t)(c + 2) * HW);
    const float2 x3 = *(const float2*)(xp + (size_t)(c + 3) * HW);
#pragma unroll
    for (int o = 0; o < CQ; ++o) {
      const float4 a = *(const float4*)(Wq + o * C + c);
      qa0[o] = fmaf(a.w, x3.x, fmaf(a.z, x2.x, fmaf(a.y, x1.x, fmaf(a.x, x0.x, qa0[o]))));
      qa1[o] = fmaf(a.w, x3.y, fmaf(a.z, x2.y, fmaf(a.y, x1.y, fmaf(a.x, x0.y, qa1[o]))));
      const float4 bb = *(const float4*)(Wk + o * C + c);
      ka0[o] = fmaf(bb.w, x3.x, fmaf(bb.z, x2.x, fmaf(bb.y, x1.x, fmaf(bb.x, x0.x, ka0[o]))));
      ka1[o] = fmaf(bb.w, x3.y, fmaf(bb.z, x2.y, fmaf(bb.y, x1.y, fmaf(bb.x, x0.y, ka1[o]))));
    }
#pragma unroll
    for (int o = 0; o < C; ++o) {
      const float4 cc = *(const float4*)(Wv + o * C + c);
      va0[o] = fmaf(cc.w, x3.x, fmaf(cc.z, x2.x, fmaf(cc.y, x1.x, fmaf(cc.x, x0.x, va0[o]))));
      va1[o] = fmaf(cc.w, x3.y, fmaf(cc.z, x2.y, fmaf(cc.y, x1.y, fmaf(cc.x, x0.y, va1[o]))));
    }
  }

  uint4 qp0, kp0, qp1, kp1;
  qp0.x = pack2(qa0[0], qa0[1]); qp0.y = pack2(qa0[2], qa0[3]);
  qp0.z = pack2(qa0[4], qa0[5]); qp0.w = pack2(qa0[6], qa0[7]);
  kp0.x = pack2(ka0[0], ka0[1]); kp0.y = pack2(ka0[2], ka0[3]);
  kp0.z = pack2(ka0[4], ka0[5]); kp0.w = pack2(ka0[6], ka0[7]);
  qp1.x = pack2(qa1[0], qa1[1]); qp1.y = pack2(qa1[2], qa1[3]);
  qp1.z = pack2(qa1[4], qa1[5]); qp1.w = pack2(qa1[6], qa1[7]);
  kp1.x = pack2(ka1[0], ka1[1]); kp1.y = pack2(ka1[2], ka1[3]);
  kp1.z = pack2(ka1[4], ka1[5]); kp1.w = pack2(ka1[6], ka1[7]);
  *(uint4*)(qwp + (size_t)pix0 * 8) = qp0;
  *(uint4*)(qwp + (size_t)(pix0 + 1) * 8) = qp1;
  *(uint4*)(kwp + (size_t)pix0 * 8) = kp0;
  *(uint4*)(kwp + (size_t)(pix0 + 1) * 8) = kp1;
  const size_t tb0 = ((size_t)b * W + w) * H + h;
  const size_t tb1 = tb0 + H;  // w+1
  *(uint4*)(qhp + tb0 * 8) = qp0;
  *(uint4*)(qhp + tb1 * 8) = qp1;
  *(uint4*)(khp + tb0 * 8) = kp0;
  *(uint4*)(khp + tb1 * 8) = kp1;

  unsigned short* vp = v + (size_t)b * C * HW + r;
#pragma unroll
  for (int o = 0; o < C; ++o)
    *(unsigned int*)(vp + (size_t)o * HW) = pack2(va0[o], va1[o]);
  unsigned short* vt0 = vt + tb0 * C;
  unsigned short* vt1 = vt + tb1 * C;
#pragma unroll
  for (int j = 0; j < 16; ++j) {
    ushort4 u0, u1;
    u0.x = f2bf(va0[4 * j + 0]); u0.y = f2bf(va0[4 * j + 1]);
    u0.z = f2bf(va0[4 * j + 2]); u0.w = f2bf(va0[4 * j + 3]);
    u1.x = f2bf(va1[4 * j + 0]); u1.y = f2bf(va1[4 * j + 1]);
    u1.z = f2bf(va1[4 * j + 2]); u1.w = f2bf(va1[4 * j + 3]);
    *(ushort4*)(vt0 + 4 * j) = u0;
    *(ushort4*)(vt1 + 4 * j) = u1;
  }
}

// ---------------------------------------------------------------------------
// K2: out_w unnormalized + S_w. R12 structure (2 blocks/(b,h), 32-row waves,
// async staging, kb prefetch, dw LDS LUT). LUT now stores dw*log2e so
// p = exp2(E*dwt) is a single v_exp_f32 after one mul (was mul+mul+exp).
// ---------------------------------------------------------------------------
constexpr int VSW = 494;

__global__ __launch_bounds__(512, 1)
void k_outw(const unsigned short* __restrict__ qwp,
            const unsigned short* __restrict__ kwp,
            const unsigned short* __restrict__ v,
            unsigned short* __restrict__ ow, float* __restrict__ Sw) {
  __shared__ __align__(16) unsigned short vbs[64 * VSW];   // 63232 B
  __shared__ __align__(16) unsigned short kls[480 * 8];    // 7680 B
  __shared__ float dwt[959];                               // 3836 B
  const int h = blockIdx.x >> 1, z = blockIdx.x & 1;
  const int b = blockIdx.y;
  const int tid = threadIdx.x;
  const size_t rowbase = ((size_t)b * H + h) * W;

  const unsigned short* vrow = v + (size_t)b * C * HW + (size_t)h * W;
  // ---- async staging: load batch 1 (8), write, load batch 2 (7), write ----
  ushort4 vr0[8];
#pragma unroll
  for (int it = 0; it < 8; ++it) {
    const int idx = tid + it * 512;
    const int c = idx / 120, s4 = (idx - c * 120) * 4;
    vr0[it] = *(const ushort4*)(vrow + (size_t)c * HW + s4);
  }
  uint4 kreg;
  if (tid < 480) kreg = *(const uint4*)(kwp + (rowbase + tid) * 8);
#pragma unroll
  for (int it = 0; it < 8; ++it) {
    const int idx = tid + it * 512;
    const int c = idx / 120, s4 = (idx - c * 120) * 4;
    const int u = s4 & 31;
    const int t = (u < 16) ? ((u >> 2) * 8) : (((u - 16) >> 2) * 8 + 4);
    *(ushort4*)(vbs + c * VSW + (s4 & ~31) + t) = vr0[it];
  }
  ushort4 vr1[7];
#pragma unroll
  for (int it = 0; it < 7; ++it) {
    const int idx = tid + (8 + it) * 512;
    const int c = idx / 120, s4 = (idx - c * 120) * 4;
    vr1[it] = *(const ushort4*)(vrow + (size_t)c * HW + s4);
  }
#pragma unroll
  for (int it = 0; it < 7; ++it) {
    const int idx = tid + (8 + it) * 512;
    const int c = idx / 120, s4 = (idx - c * 120) * 4;
    const int u = s4 & 31;
    const int t = (u < 16) ? ((u >> 2) * 8) : (((u - 16) >> 2) * 8 + 4);
    *(ushort4*)(vbs + c * VSW + (s4 & ~31) + t) = vr1[it];
  }
  if (tid < 480) *(uint4*)(kls + tid * 8) = kreg;
  for (int i2 = tid; i2 < 959; i2 += 512) {
    const float d = (float)(i2 - 479);
    dwt[i2] = LOG2E * __expf(-(d * d) * INVW2);
  }

  const int lane = tid & 63, wv = tid >> 6;
  const int l15 = lane & 15, quad = lane >> 4;
  const int chunk = z * 8 + wv;
  const bool active = chunk < 15;
  const int m0 = chunk * 32;

  short8 qa0 = short8{0, 0, 0, 0, 0, 0, 0, 0};
  short8 qa1 = short8{0, 0, 0, 0, 0, 0, 0, 0};
  if (quad == 0 && active) {
    qa0 = *(const short8*)(qwp + (rowbase + m0 + l15) * 8);
    qa1 = *(const short8*)(qwp + (rowbase + m0 + 16 + l15) * 8);
  }

  f32x4 acc[2][4];
  float Sacc[2] = {0.0f, 0.0f};
#pragma unroll
  for (int mt = 0; mt < 2; ++mt)
#pragma unroll
    for (int ct = 0; ct < 4; ++ct)
#pragma unroll
      for (int rr = 0; rr < 4; ++rr) acc[mt][ct][rr] = 0.0f;

  __syncthreads();

  if (active) {
    short8 kb0 = short8{0, 0, 0, 0, 0, 0, 0, 0};
    short8 kb1 = short8{0, 0, 0, 0, 0, 0, 0, 0};
    if (quad == 0) {
      kb0 = *(const short8*)(kls + (l15) * 8);
      kb1 = *(const short8*)(kls + (16 + l15) * 8);
    }
    for (int ci = 0; ci < 15; ++ci) {
      const int sc = ci * 32;
      short8 nk0 = short8{0, 0, 0, 0, 0, 0, 0, 0};
      short8 nk1 = short8{0, 0, 0, 0, 0, 0, 0, 0};
      if (ci < 14 && quad == 0) {
        nk0 = *(const short8*)(kls + (sc + 32 + l15) * 8);
        nk1 = *(const short8*)(kls + (sc + 48 + l15) * 8);
      }
      short8 vb[4];
#pragma unroll
      for (int ct = 0; ct < 4; ++ct)
        vb[ct] = *(const short8*)(vbs + (ct * 16 + l15) * VSW + sc + quad * 8);
      const f32x4 z4 = f32x4{0.f, 0.f, 0.f, 0.f};
      const f32x4 E00 = __builtin_amdgcn_mfma_f32_16x16x32_bf16(kb0, qa0, z4, 0, 0, 0);
      const f32x4 E01 = __builtin_amdgcn_mfma_f32_16x16x32_bf16(kb1, qa0, z4, 0, 0, 0);
      const f32x4 E10 = __builtin_amdgcn_mfma_f32_16x16x32_bf16(kb0, qa1, z4, 0, 0, 0);
      const f32x4 E11 = __builtin_amdgcn_mfma_f32_16x16x32_bf16(kb1, qa1, z4, 0, 0, 0);
#pragma unroll
      for (int mt = 0; mt < 2; ++mt) {
        const int m = m0 + mt * 16 + l15;
        const int base = m + 479 - quad * 4 - sc;  // dwt idx for rr=0 (p0)
        const f32x4 Ea = mt ? E10 : E00;
        const f32x4 Eb = mt ? E11 : E01;
        float p0[4], p1[4];
#pragma unroll
        for (int rr = 0; rr < 4; ++rr) {
          p0[rr] = EXP2F(Ea[rr] * dwt[base - rr]);
          p1[rr] = EXP2F(Eb[rr] * dwt[base - 16 - rr]);
          Sacc[mt] += p0[rr] + p1[rr];
        }
        const short8 pa = pack_p(p0, p1);
#pragma unroll
        for (int ct = 0; ct < 4; ++ct)
          acc[mt][ct] = __builtin_amdgcn_mfma_f32_16x16x32_bf16(pa, vb[ct], acc[mt][ct], 0, 0, 0);
      }
      kb0 = nk0;
      kb1 = nk1;
    }

#pragma unroll
    for (int mt = 0; mt < 2; ++mt) {
      float s = Sacc[mt];
      s += __shfl_xor(s, 16);
      s += __shfl_xor(s, 32);
      if (lane < 16) Sw[rowbase + m0 + mt * 16 + l15] = s;
    }
  }

  __syncthreads();  // vbs reads done; reuse as [c][480] transpose buffer
  unsigned short* ob = vbs;
  if (active) {
#pragma unroll
    for (int mt = 0; mt < 2; ++mt)
#pragma unroll
      for (int ct = 0; ct < 4; ++ct)
#pragma unroll
        for (int rr = 0; rr < 4; ++rr)
          ob[(ct * 16 + l15) * VSW + m0 + mt * 16 + quad * 4 + rr] = f2bf(acc[mt][ct][rr]);
  }
  __syncthreads();
  unsigned short* og = ow + ((size_t)b * H + h) * C * W;
  const int mlo = z ? 256 : 0;
  const int nu = z ? 112 : 128;  // u32 per c-row in this block's m-range
  for (int idx = tid; idx < 64 * nu; idx += 512) {
    const int c = idx / nu, i = idx - c * nu;
    *(unsigned int*)(og + (size_t)c * W + mlo + 2 * i) =
        *(const unsigned int*)(ob + c * VSW + mlo + 2 * i);
  }
}

// ---------------------------------------------------------------------------
// K3: out_h unnormalized + S_h. R12 16-row-wave structure + dw LUT (exp2-
// folded). kb prefetch REVERTED (R13 showed it regresses ~1-2 us at 4.5
// waves/SIMD: TLP already covers the ds_read latency).
// ---------------------------------------------------------------------------
constexpr int VSH = 302;

__global__ __launch_bounds__(576, 1)
void k_outh(const unsigned short* __restrict__ qhp,
            const unsigned short* __restrict__ khp,
            const unsigned short* __restrict__ vt,
            unsigned short* __restrict__ oht, float* __restrict__ Sht) {
  __shared__ __align__(16) unsigned short vbs[64 * VSH];   // 38656 B
  __shared__ __align__(16) unsigned short kls[288 * 8];    // 4608 B
  __shared__ float dwt[575];                               // 2300 B
  const int w = blockIdx.x >> 1, z = blockIdx.x & 1;
  const int b = blockIdx.y;
  const int tid = threadIdx.x;
  const size_t colbase = ((size_t)b * W + w) * H;

  const unsigned short* vtb = vt + colbase * C;
  // ---- async staging: 288*16 = 4608 = 8*576 exactly ----
  ushort4 vreg[8];
#pragma unroll
  for (int it = 0; it < 8; ++it) {
    const int idx = tid + it * 576;
    const int g = idx >> 4, c4 = (idx & 15) * 4;
    vreg[it] = (g < H) ? *(const ushort4*)(vtb + (size_t)g * C + c4)
                       : make_ushort4(0, 0, 0, 0);
  }
  uint4 kreg;
  if (tid < 288) kreg = *(const uint4*)(khp + (colbase + min(tid, H - 1)) * 8);
#pragma unroll
  for (int it = 0; it < 8; ++it) {
    const int idx = tid + it * 576;
    const int g = idx >> 4, c4 = (idx & 15) * 4;
    const int u = g & 31;
    const int t = (u < 16) ? ((u >> 2) * 8 + (u & 3))
                           : (((u - 16) >> 2) * 8 + 4 + (u & 3));
    const int slot = (g & ~31) + t;
    vbs[(c4 + 0) * VSH + slot] = vreg[it].x;
    vbs[(c4 + 1) * VSH + slot] = vreg[it].y;
    vbs[(c4 + 2) * VSH + slot] = vreg[it].z;
    vbs[(c4 + 3) * VSH + slot] = vreg[it].w;
  }
  if (tid < 288) *(uint4*)(kls + tid * 8) = kreg;
  if (tid < 575) {
    const float d = (float)(tid - 287);
    dwt[tid] = LOG2E * __expf(-(d * d) * INVH2);
  }

  const int lane = tid & 63, wv = tid >> 6;
  const int l15 = lane & 15, quad = lane >> 4;
  const int m0 = (z * 9 + wv) * 16;
  const int m = m0 + l15;  // this lane's m-row

  short8 qa = short8{0, 0, 0, 0, 0, 0, 0, 0};
  if (quad == 0)
    qa = *(const short8*)(qhp + (colbase + min(m, H - 1)) * 8);

  f32x4 acc[4];
  float Sacc = 0.0f;
#pragma unroll
  for (int ct = 0; ct < 4; ++ct)
#pragma unroll
    for (int rr = 0; rr < 4; ++rr) acc[ct][rr] = 0.0f;

  __syncthreads();

  for (int ci = 0; ci < 9; ++ci) {
    const int gc = ci * 32;
    short8 kb0 = short8{0, 0, 0, 0, 0, 0, 0, 0};
    short8 kb1 = short8{0, 0, 0, 0, 0, 0, 0, 0};
    if (quad == 0) {
      kb0 = *(const short8*)(kls + (gc + l15) * 8);
      kb1 = *(const short8*)(kls + (gc + 16 + l15) * 8);
    }
    short8 vb[4];
#pragma unroll
    for (int ct = 0; ct < 4; ++ct)
      vb[ct] = *(const short8*)(vbs + (ct * 16 + l15) * VSH + gc + quad * 8);
    const f32x4 z4 = f32x4{0.f, 0.f, 0.f, 0.f};
    const f32x4 E0 = __builtin_amdgcn_mfma_f32_16x16x32_bf16(kb0, qa, z4, 0, 0, 0);
    const f32x4 E1 = __builtin_amdgcn_mfma_f32_16x16x32_bf16(kb1, qa, z4, 0, 0, 0);
    const int base = m + 287 - quad * 4 - gc;  // dwt idx for rr=0 (p0)
    float p0[4], p1[4];
#pragma unroll
    for (int rr = 0; rr < 4; ++rr) {
      const int g0 = gc + quad * 4 + rr;
      const int g1 = g0 + 16;
      p0[rr] = (g0 < H && g0 != m)
                   ? EXP2F(E0[rr] * dwt[base - rr]) : 0.0f;
      p1[rr] = (g1 < H && g1 != m)
                   ? EXP2F(E1[rr] * dwt[base - 16 - rr]) : 0.0f;
      Sacc += p0[rr] + p1[rr];
    }
    const short8 pa = pack_p(p0, p1);
#pragma unroll
    for (int ct = 0; ct < 4; ++ct)
      acc[ct] = __builtin_amdgcn_mfma_f32_16x16x32_bf16(pa, vb[ct], acc[ct], 0, 0, 0);
  }

  {
    float s = Sacc;
    s += __shfl_xor(s, 16);
    s += __shfl_xor(s, 32);
    if (lane < 16 && m < H) Sht[colbase + m] = s;
  }

  __syncthreads();
  unsigned short* ob = vbs;  // [c][288] stride VSH
#pragma unroll
  for (int ct = 0; ct < 4; ++ct)
#pragma unroll
    for (int rr = 0; rr < 4; ++rr)
      ob[(ct * 16 + l15) * VSH + m0 + quad * 4 + rr] = f2bf(acc[ct][rr]);
  __syncthreads();
  unsigned short* og = oht + ((size_t)b * W + w) * C * H;
  const int mlo = z ? 144 : 0;
  const int nu = z ? 63 : 72;  // u32 per c-row: z=0 rows 0-143, z=1 rows 144-269
  for (int idx = tid; idx < 64 * nu; idx += 576) {
    const int c = idx / nu, i = idx - c * nu;
    *(unsigned int*)(og + (size_t)c * H + mlo + 2 * i) =
        *(const unsigned int*)(ob + c * VSH + mlo + 2 * i);
  }
}

// ---------------------------------------------------------------------------
// K3b: invZ[b][h][w] = 1/(Sh+Sw), computed ONCE instead of redundantly per
// c-block in k_combine (64x).
// ---------------------------------------------------------------------------
__global__ __launch_bounds__(256)
void k_invz(const float* __restrict__ Sht, const float* __restrict__ Sw,
            float* __restrict__ invZ) {
  const int i = blockIdx.x * 256 + threadIdx.x;
  if (i >= B * HW) return;
  const int b = i / HW;
  const int r = i - b * HW;
  const int h = r / W;
  const int w = r - h * W;
  const float z = Sht[((size_t)b * W + w) * H + h] + Sw[i];
  invZ[i] = __builtin_amdgcn_rcpf(z);
}

// ---------------------------------------------------------------------------
// K4: out = gamma*(U_h + U_w)*invZ + x, LDS tile transpose for oht.
// ---------------------------------------------------------------------------
__global__ __launch_bounds__(256)
void k_combine(const unsigned short* __restrict__ oht,
               const unsigned short* __restrict__ ow,
               const float* __restrict__ izp,
               const float* __restrict__ x,
               const float* __restrict__ gp,
               float* __restrict__ out) {
  __shared__ float tile[32][33];
  const int b = blockIdx.z >> 6, c = blockIdx.z & 63;
  const int w0 = blockIdx.x * 32, h0 = blockIdx.y * 32;
  const int tx = threadIdx.x, ty = threadIdx.y;  // (32, 8)
#pragma unroll
  for (int i = 0; i < 4; ++i) {
    const int wl = ty + i * 8;
    const int hh = h0 + tx;
    float val = 0.0f;
    if (hh < H) val = bits2f(oht[(((size_t)b * W + (w0 + wl)) * C + c) * H + hh]);
    tile[wl][tx] = val;
  }
  __syncthreads();
  const float gamma = *gp;
#pragma unroll
  for (int i = 0; i < 4; ++i) {
    const int hl = ty + i * 8;
    const int hh = h0 + hl;
    if (hh < H) {
      const int ww = w0 + tx;
      const float uh = tile[tx][hl];
      const float uw = bits2f(ow[(((size_t)b * H + hh) * C + c) * W + ww]);
      const size_t si = ((size_t)b * H + hh) * W + ww;
      const float invZ = izp[si];
      const size_t xi = ((size_t)b * C + c) * HW + (size_t)hh * W + ww;
      out[xi] = fmaf(gamma * invZ, uh + uw, x[xi]);
    }
  }
}

}  // namespace

extern "C" void kernel_launch(void* const* d_in, const int* in_sizes, int n_in,
                              void* d_out, int out_size, void* d_ws, size_t ws_size,
                              hipStream_t stream) {
  (void)in_sizes; (void)n_in; (void)out_size; (void)ws_size;
  const float* x  = (const float*)d_in[0];
  const float* Wq = (const float*)d_in[1];
  const float* bq = (const float*)d_in[2];
  const float* Wk = (const float*)d_in[3];
  const float* bk = (const float*)d_in[4];
  const float* Wv = (const float*)d_in[5];
  const float* bv = (const float*)d_in[6];
  const float* gp = (const float*)d_in[7];
  float* out = (float*)d_out;

  char* p = (char*)d_ws;
  auto take = [&](size_t bytes) -> void* {
    char* r = p;
    p += (bytes + 255) & ~(size_t)255;
    return (void*)r;
  };
  unsigned short* qwp = (unsigned short*)take(sizeof(unsigned short) * (size_t)B * HW * 8);
  unsigned short* kwp = (unsigned short*)take(sizeof(unsigned short) * (size_t)B * HW * 8);
  unsigned short* qhp = (unsigned short*)take(sizeof(unsigned short) * (size_t)B * HW * 8);
  unsigned short* khp = (unsigned short*)take(sizeof(unsigned short) * (size_t)B * HW * 8);
  unsigned short* v   = (unsigned short*)take(sizeof(unsigned short) * (size_t)B * C * HW);
  unsigned short* vt  = (unsigned short*)take(sizeof(unsigned short) * (size_t)B * C * HW);
  unsigned short* oht = (unsigned short*)take(sizeof(unsigned short) * (size_t)B * C * HW);
  unsigned short* owb = (unsigned short*)take(sizeof(unsigned short) * (size_t)B * C * HW);
  float* Sht = (float*)take(sizeof(float) * (size_t)B * HW);
  float* Sw  = (float*)take(sizeof(float) * (size_t)B * HW);
  float* izb = (float*)take(sizeof(float) * (size_t)B * HW);

  hipLaunchKernelGGL(k_qkv, dim3((B * HW / 2 + 255) / 256), dim3(256), 0, stream,
                     x, Wq, bq, Wk, bk, Wv, bv, qwp, kwp, qhp, khp, v, vt);
  hipLaunchKernelGGL(k_outh, dim3(2 * W, B), dim3(576), 0, stream,
                     qhp, khp, vt, oht, Sht);
  hipLaunchKernelGGL(k_outw, dim3(2 * H, B), dim3(512), 0, stream,
                     qwp, kwp, v, owb, Sw);
  hipLaunchKernelGGL(k_invz, dim3((B * HW + 255) / 256), dim3(256), 0, stream,
                     Sht, Sw, izb);
  hipLaunchKernelGGL(k_combine, dim3(W / 32, (H + 31) / 32, B * C), dim3(32, 8), 0, stream,
                     oht, owb, izb, x, gp, out);
}

// Round 15
// 370.665 us; speedup vs baseline: 1.1169x; 1.1169x over previous
//
#include <hip/hip_runtime.h>
#include <hip/hip_bf16.h>

namespace {

constexpr int B  = 2;
constexpr int C  = 64;
constexpr int CQ = 8;
constexpr int H  = 270;
constexpr int W  = 480;
constexpr int HW = H * W;
constexpr float INVH2 = 2.0f / (270.0f * 270.0f);  // dw_h = exp(-d^2 * INVH2)
constexpr float INVW2 = 2.0f / (480.0f * 480.0f);
constexpr float LOG2E = 1.44269504088896340736f;

#if __has_builtin(__builtin_amdgcn_exp2f)
#define EXP2F(x) __builtin_amdgcn_exp2f(x)
#else
#define EXP2F(x) exp2f(x)
#endif

typedef __attribute__((ext_vector_type(4))) float f32x4;
typedef __attribute__((ext_vector_type(8))) short short8;
typedef __attribute__((ext_vector_type(4))) unsigned int uint4v;

__device__ __forceinline__ float bits2f(unsigned short u) {
  union { unsigned int i; float f; } cv;
  cv.i = ((unsigned int)u) << 16;
  return cv.f;
}

__device__ __forceinline__ unsigned short f2bf(float f) {
  union { __hip_bfloat16 b; unsigned short u; } cv;
  cv.b = __float2bfloat16(f);
  return cv.u;
}

__device__ __forceinline__ unsigned int pack2(float a, float b) {
  return ((unsigned int)f2bf(b) << 16) | (unsigned int)f2bf(a);
}

__device__ __forceinline__ short8 pack_p(const float p0[4], const float p1[4]) {
  uint4v pw;
  pw[0] = pack2(p0[0], p0[1]);
  pw[1] = pack2(p0[2], p0[3]);
  pw[2] = pack2(p1[0], p1[1]);
  pw[3] = pack2(p1[2], p1[3]);
  return __builtin_bit_cast(short8, pw);
}

// V-row permutation inside each 32-row K-step so that the swapped-QK P layout
// (lane quad q holds g = 4q+rr from E0 and 16+4q+rr from E1) feeds the PV
// A-fragment (k-slot q*8+j) with NO cross-lane data movement:
//   u < 16: slot = 8*(u>>2) + (u&3);  u >= 16: slot = 8*((u-16)>>2) + 4 + (u&3)

// ---------------------------------------------------------------------------
// K1: q/k/v 1x1 projections, two adjacent pixels per thread, weights staged
// in LDS (R10's measured-best form, ~80us). R14's scalar-load variant
// REVERTED: s_load per c-step serializes on lgkmcnt (125us, VALUBusy 35%) —
// the SGPR file can't hold 20KB of weights, so LDS broadcast (co-issues with
// VALU) is strictly better.
// ---------------------------------------------------------------------------
__global__ __launch_bounds__(256, 1)
void k_qkv(const float* __restrict__ x,
           const float* __restrict__ Wq, const float* __restrict__ bq,
           const float* __restrict__ Wk, const float* __restrict__ bk,
           const float* __restrict__ Wv, const float* __restrict__ bv,
           unsigned short* __restrict__ qwp, unsigned short* __restrict__ kwp,
           unsigned short* __restrict__ qhp, unsigned short* __restrict__ khp,
           unsigned short* __restrict__ v, unsigned short* __restrict__ vt) {
  __shared__ __align__(16) float wql[CQ * C];
  __shared__ __align__(16) float wkl[CQ * C];
  __shared__ __align__(16) float wvl[C * C];
  __shared__ float bql[CQ], bkl[CQ], bvl[C];
  const int tid = threadIdx.x;
  for (int i = tid; i < CQ * C; i += 256) { wql[i] = Wq[i]; wkl[i] = Wk[i]; }
  for (int i = tid; i < C * C; i += 256) wvl[i] = Wv[i];
  if (tid < CQ) { bql[tid] = bq[tid]; bkl[tid] = bk[tid]; }
  if (tid < C) bvl[tid] = bv[tid];
  __syncthreads();
  const int pix0 = (blockIdx.x * 256 + tid) * 2;
  if (pix0 >= B * HW) return;
  const int b = pix0 / HW;
  const int r = pix0 - b * HW;   // even; pixels r and r+1 share b and h
  const int h = r / W;
  const int w = r - h * W;       // even; w+1 < W

  float qa0[CQ], qa1[CQ], ka0[CQ], ka1[CQ], va0[C], va1[C];
#pragma unroll
  for (int o = 0; o < CQ; ++o) {
    qa0[o] = bql[o]; qa1[o] = bql[o];
    ka0[o] = bkl[o]; ka1[o] = bkl[o];
  }
#pragma unroll
  for (int o = 0; o < C; ++o) { va0[o] = bvl[o]; va1[o] = bvl[o]; }

  const float* xp = x + (size_t)b * C * HW + r;
  for (int c = 0; c < C; c += 4) {
    const float2 x0 = *(const float2*)(xp + (size_t)(c + 0) * HW);
    const float2 x1 = *(const float2*)(xp + (size_t)(c + 1) * HW);
    const float2 x2 = *(const float2*)(xp + (size_t)(c + 2) * HW);
    const float2 x3 = *(const float2*)(xp + (size_t)(c + 3) * HW);
#pragma unroll
    for (int o = 0; o < CQ; ++o) {
      const float4 a = *(const float4*)(wql + o * C + c);
      qa0[o] = fmaf(a.w, x3.x, fmaf(a.z, x2.x, fmaf(a.y, x1.x, fmaf(a.x, x0.x, qa0[o]))));
      qa1[o] = fmaf(a.w, x3.y, fmaf(a.z, x2.y, fmaf(a.y, x1.y, fmaf(a.x, x0.y, qa1[o]))));
      const float4 bb = *(const float4*)(wkl + o * C + c);
      ka0[o] = fmaf(bb.w, x3.x, fmaf(bb.z, x2.x, fmaf(bb.y, x1.x, fmaf(bb.x, x0.x, ka0[o]))));
      ka1[o] = fmaf(bb.w, x3.y, fmaf(bb.z, x2.y, fmaf(bb.y, x1.y, fmaf(bb.x, x0.y, ka1[o]))));
    }
#pragma unroll
    for (int o = 0; o < C; ++o) {
      const float4 cc = *(const float4*)(wvl + o * C + c);
      va0[o] = fmaf(cc.w, x3.x, fmaf(cc.z, x2.x, fmaf(cc.y, x1.x, fmaf(cc.x, x0.x, va0[o]))));
      va1[o] = fmaf(cc.w, x3.y, fmaf(cc.z, x2.y, fmaf(cc.y, x1.y, fmaf(cc.x, x0.y, va1[o]))));
    }
  }

  uint4 qp0, kp0, qp1, kp1;
  qp0.x = pack2(qa0[0], qa0[1]); qp0.y = pack2(qa0[2], qa0[3]);
  qp0.z = pack2(qa0[4], qa0[5]); qp0.w = pack2(qa0[6], qa0[7]);
  kp0.x = pack2(ka0[0], ka0[1]); kp0.y = pack2(ka0[2], ka0[3]);
  kp0.z = pack2(ka0[4], ka0[5]); kp0.w = pack2(ka0[6], ka0[7]);
  qp1.x = pack2(qa1[0], qa1[1]); qp1.y = pack2(qa1[2], qa1[3]);
  qp1.z = pack2(qa1[4], qa1[5]); qp1.w = pack2(qa1[6], qa1[7]);
  kp1.x = pack2(ka1[0], ka1[1]); kp1.y = pack2(ka1[2], ka1[3]);
  kp1.z = pack2(ka1[4], ka1[5]); kp1.w = pack2(ka1[6], ka1[7]);
  *(uint4*)(qwp + (size_t)pix0 * 8) = qp0;
  *(uint4*)(qwp + (size_t)(pix0 + 1) * 8) = qp1;
  *(uint4*)(kwp + (size_t)pix0 * 8) = kp0;
  *(uint4*)(kwp + (size_t)(pix0 + 1) * 8) = kp1;
  const size_t tb0 = ((size_t)b * W + w) * H + h;
  const size_t tb1 = tb0 + H;  // w+1
  *(uint4*)(qhp + tb0 * 8) = qp0;
  *(uint4*)(qhp + tb1 * 8) = qp1;
  *(uint4*)(khp + tb0 * 8) = kp0;
  *(uint4*)(khp + tb1 * 8) = kp1;

  unsigned short* vp = v + (size_t)b * C * HW + r;
#pragma unroll
  for (int o = 0; o < C; ++o)
    *(unsigned int*)(vp + (size_t)o * HW) = pack2(va0[o], va1[o]);
  unsigned short* vt0 = vt + tb0 * C;
  unsigned short* vt1 = vt + tb1 * C;
#pragma unroll
  for (int j = 0; j < 16; ++j) {
    ushort4 u0, u1;
    u0.x = f2bf(va0[4 * j + 0]); u0.y = f2bf(va0[4 * j + 1]);
    u0.z = f2bf(va0[4 * j + 2]); u0.w = f2bf(va0[4 * j + 3]);
    u1.x = f2bf(va1[4 * j + 0]); u1.y = f2bf(va1[4 * j + 1]);
    u1.z = f2bf(va1[4 * j + 2]); u1.w = f2bf(va1[4 * j + 3]);
    *(ushort4*)(vt0 + 4 * j) = u0;
    *(ushort4*)(vt1 + 4 * j) = u1;
  }
}

// ---------------------------------------------------------------------------
// K2: out_w unnormalized + S_w. R12 structure (2 blocks/(b,h), 32-row waves,
// async staging, kb prefetch) + exp2-folded dw LUT (p = exp2(E*dwt), one
// v_exp_f32 after one mul).
// ---------------------------------------------------------------------------
constexpr int VSW = 494;

__global__ __launch_bounds__(512, 1)
void k_outw(const unsigned short* __restrict__ qwp,
            const unsigned short* __restrict__ kwp,
            const unsigned short* __restrict__ v,
            unsigned short* __restrict__ ow, float* __restrict__ Sw) {
  __shared__ __align__(16) unsigned short vbs[64 * VSW];   // 63232 B
  __shared__ __align__(16) unsigned short kls[480 * 8];    // 7680 B
  __shared__ float dwt[959];                               // 3836 B
  const int h = blockIdx.x >> 1, z = blockIdx.x & 1;
  const int b = blockIdx.y;
  const int tid = threadIdx.x;
  const size_t rowbase = ((size_t)b * H + h) * W;

  const unsigned short* vrow = v + (size_t)b * C * HW + (size_t)h * W;
  // ---- async staging: load batch 1 (8), write, load batch 2 (7), write ----
  ushort4 vr0[8];
#pragma unroll
  for (int it = 0; it < 8; ++it) {
    const int idx = tid + it * 512;
    const int c = idx / 120, s4 = (idx - c * 120) * 4;
    vr0[it] = *(const ushort4*)(vrow + (size_t)c * HW + s4);
  }
  uint4 kreg;
  if (tid < 480) kreg = *(const uint4*)(kwp + (rowbase + tid) * 8);
#pragma unroll
  for (int it = 0; it < 8; ++it) {
    const int idx = tid + it * 512;
    const int c = idx / 120, s4 = (idx - c * 120) * 4;
    const int u = s4 & 31;
    const int t = (u < 16) ? ((u >> 2) * 8) : (((u - 16) >> 2) * 8 + 4);
    *(ushort4*)(vbs + c * VSW + (s4 & ~31) + t) = vr0[it];
  }
  ushort4 vr1[7];
#pragma unroll
  for (int it = 0; it < 7; ++it) {
    const int idx = tid + (8 + it) * 512;
    const int c = idx / 120, s4 = (idx - c * 120) * 4;
    vr1[it] = *(const ushort4*)(vrow + (size_t)c * HW + s4);
  }
#pragma unroll
  for (int it = 0; it < 7; ++it) {
    const int idx = tid + (8 + it) * 512;
    const int c = idx / 120, s4 = (idx - c * 120) * 4;
    const int u = s4 & 31;
    const int t = (u < 16) ? ((u >> 2) * 8) : (((u - 16) >> 2) * 8 + 4);
    *(ushort4*)(vbs + c * VSW + (s4 & ~31) + t) = vr1[it];
  }
  if (tid < 480) *(uint4*)(kls + tid * 8) = kreg;
  for (int i2 = tid; i2 < 959; i2 += 512) {
    const float d = (float)(i2 - 479);
    dwt[i2] = LOG2E * __expf(-(d * d) * INVW2);
  }

  const int lane = tid & 63, wv = tid >> 6;
  const int l15 = lane & 15, quad = lane >> 4;
  const int chunk = z * 8 + wv;
  const bool active = chunk < 15;
  const int m0 = chunk * 32;

  short8 qa0 = short8{0, 0, 0, 0, 0, 0, 0, 0};
  short8 qa1 = short8{0, 0, 0, 0, 0, 0, 0, 0};
  if (quad == 0 && active) {
    qa0 = *(const short8*)(qwp + (rowbase + m0 + l15) * 8);
    qa1 = *(const short8*)(qwp + (rowbase + m0 + 16 + l15) * 8);
  }

  f32x4 acc[2][4];
  float Sacc[2] = {0.0f, 0.0f};
#pragma unroll
  for (int mt = 0; mt < 2; ++mt)
#pragma unroll
    for (int ct = 0; ct < 4; ++ct)
#pragma unroll
      for (int rr = 0; rr < 4; ++rr) acc[mt][ct][rr] = 0.0f;

  __syncthreads();

  if (active) {
    short8 kb0 = short8{0, 0, 0, 0, 0, 0, 0, 0};
    short8 kb1 = short8{0, 0, 0, 0, 0, 0, 0, 0};
    if (quad == 0) {
      kb0 = *(const short8*)(kls + (l15) * 8);
      kb1 = *(const short8*)(kls + (16 + l15) * 8);
    }
    for (int ci = 0; ci < 15; ++ci) {
      const int sc = ci * 32;
      short8 nk0 = short8{0, 0, 0, 0, 0, 0, 0, 0};
      short8 nk1 = short8{0, 0, 0, 0, 0, 0, 0, 0};
      if (ci < 14 && quad == 0) {
        nk0 = *(const short8*)(kls + (sc + 32 + l15) * 8);
        nk1 = *(const short8*)(kls + (sc + 48 + l15) * 8);
      }
      short8 vb[4];
#pragma unroll
      for (int ct = 0; ct < 4; ++ct)
        vb[ct] = *(const short8*)(vbs + (ct * 16 + l15) * VSW + sc + quad * 8);
      const f32x4 z4 = f32x4{0.f, 0.f, 0.f, 0.f};
      const f32x4 E00 = __builtin_amdgcn_mfma_f32_16x16x32_bf16(kb0, qa0, z4, 0, 0, 0);
      const f32x4 E01 = __builtin_amdgcn_mfma_f32_16x16x32_bf16(kb1, qa0, z4, 0, 0, 0);
      const f32x4 E10 = __builtin_amdgcn_mfma_f32_16x16x32_bf16(kb0, qa1, z4, 0, 0, 0);
      const f32x4 E11 = __builtin_amdgcn_mfma_f32_16x16x32_bf16(kb1, qa1, z4, 0, 0, 0);
#pragma unroll
      for (int mt = 0; mt < 2; ++mt) {
        const int m = m0 + mt * 16 + l15;
        const int base = m + 479 - quad * 4 - sc;  // dwt idx for rr=0 (p0)
        const f32x4 Ea = mt ? E10 : E00;
        const f32x4 Eb = mt ? E11 : E01;
        float p0[4], p1[4];
#pragma unroll
        for (int rr = 0; rr < 4; ++rr) {
          p0[rr] = EXP2F(Ea[rr] * dwt[base - rr]);
          p1[rr] = EXP2F(Eb[rr] * dwt[base - 16 - rr]);
          Sacc[mt] += p0[rr] + p1[rr];
        }
        const short8 pa = pack_p(p0, p1);
#pragma unroll
        for (int ct = 0; ct < 4; ++ct)
          acc[mt][ct] = __builtin_amdgcn_mfma_f32_16x16x32_bf16(pa, vb[ct], acc[mt][ct], 0, 0, 0);
      }
      kb0 = nk0;
      kb1 = nk1;
    }

#pragma unroll
    for (int mt = 0; mt < 2; ++mt) {
      float s = Sacc[mt];
      s += __shfl_xor(s, 16);
      s += __shfl_xor(s, 32);
      if (lane < 16) Sw[rowbase + m0 + mt * 16 + l15] = s;
    }
  }

  __syncthreads();  // vbs reads done; reuse as [c][480] transpose buffer
  unsigned short* ob = vbs;
  if (active) {
#pragma unroll
    for (int mt = 0; mt < 2; ++mt)
#pragma unroll
      for (int ct = 0; ct < 4; ++ct)
#pragma unroll
        for (int rr = 0; rr < 4; ++rr)
          ob[(ct * 16 + l15) * VSW + m0 + mt * 16 + quad * 4 + rr] = f2bf(acc[mt][ct][rr]);
  }
  __syncthreads();
  unsigned short* og = ow + ((size_t)b * H + h) * C * W;
  const int mlo = z ? 256 : 0;
  const int nu = z ? 112 : 128;  // u32 per c-row in this block's m-range
  for (int idx = tid; idx < 64 * nu; idx += 512) {
    const int c = idx / nu, i = idx - c * nu;
    *(unsigned int*)(og + (size_t)c * W + mlo + 2 * i) =
        *(const unsigned int*)(ob + c * VSW + mlo + 2 * i);
  }
}

// ---------------------------------------------------------------------------
// K3: out_h unnormalized + S_h. R12 16-row-wave structure (no kb prefetch)
// + exp2-folded dw LUT.
// ---------------------------------------------------------------------------
constexpr int VSH = 302;

__global__ __launch_bounds__(576, 1)
void k_outh(const unsigned short* __restrict__ qhp,
            const unsigned short* __restrict__ khp,
            const unsigned short* __restrict__ vt,
            unsigned short* __restrict__ oht, float* __restrict__ Sht) {
  __shared__ __align__(16) unsigned short vbs[64 * VSH];   // 38656 B
  __shared__ __align__(16) unsigned short kls[288 * 8];    // 4608 B
  __shared__ float dwt[575];                               // 2300 B
  const int w = blockIdx.x >> 1, z = blockIdx.x & 1;
  const int b = blockIdx.y;
  const int tid = threadIdx.x;
  const size_t colbase = ((size_t)b * W + w) * H;

  const unsigned short* vtb = vt + colbase * C;
  // ---- async staging: 288*16 = 4608 = 8*576 exactly ----
  ushort4 vreg[8];
#pragma unroll
  for (int it = 0; it < 8; ++it) {
    const int idx = tid + it * 576;
    const int g = idx >> 4, c4 = (idx & 15) * 4;
    vreg[it] = (g < H) ? *(const ushort4*)(vtb + (size_t)g * C + c4)
                       : make_ushort4(0, 0, 0, 0);
  }
  uint4 kreg;
  if (tid < 288) kreg = *(const uint4*)(khp + (colbase + min(tid, H - 1)) * 8);
#pragma unroll
  for (int it = 0; it < 8; ++it) {
    const int idx = tid + it * 576;
    const int g = idx >> 4, c4 = (idx & 15) * 4;
    const int u = g & 31;
    const int t = (u < 16) ? ((u >> 2) * 8 + (u & 3))
                           : (((u - 16) >> 2) * 8 + 4 + (u & 3));
    const int slot = (g & ~31) + t;
    vbs[(c4 + 0) * VSH + slot] = vreg[it].x;
    vbs[(c4 + 1) * VSH + slot] = vreg[it].y;
    vbs[(c4 + 2) * VSH + slot] = vreg[it].z;
    vbs[(c4 + 3) * VSH + slot] = vreg[it].w;
  }
  if (tid < 288) *(uint4*)(kls + tid * 8) = kreg;
  if (tid < 575) {
    const float d = (float)(tid - 287);
    dwt[tid] = LOG2E * __expf(-(d * d) * INVH2);
  }

  const int lane = tid & 63, wv = tid >> 6;
  const int l15 = lane & 15, quad = lane >> 4;
  const int m0 = (z * 9 + wv) * 16;
  const int m = m0 + l15;  // this lane's m-row

  short8 qa = short8{0, 0, 0, 0, 0, 0, 0, 0};
  if (quad == 0)
    qa = *(const short8*)(qhp + (colbase + min(m, H - 1)) * 8);

  f32x4 acc[4];
  float Sacc = 0.0f;
#pragma unroll
  for (int ct = 0; ct < 4; ++ct)
#pragma unroll
    for (int rr = 0; rr < 4; ++rr) acc[ct][rr] = 0.0f;

  __syncthreads();

  for (int ci = 0; ci < 9; ++ci) {
    const int gc = ci * 32;
    short8 kb0 = short8{0, 0, 0, 0, 0, 0, 0, 0};
    short8 kb1 = short8{0, 0, 0, 0, 0, 0, 0, 0};
    if (quad == 0) {
      kb0 = *(const short8*)(kls + (gc + l15) * 8);
      kb1 = *(const short8*)(kls + (gc + 16 + l15) * 8);
    }
    short8 vb[4];
#pragma unroll
    for (int ct = 0; ct < 4; ++ct)
      vb[ct] = *(const short8*)(vbs + (ct * 16 + l15) * VSH + gc + quad * 8);
    const f32x4 z4 = f32x4{0.f, 0.f, 0.f, 0.f};
    const f32x4 E0 = __builtin_amdgcn_mfma_f32_16x16x32_bf16(kb0, qa, z4, 0, 0, 0);
    const f32x4 E1 = __builtin_amdgcn_mfma_f32_16x16x32_bf16(kb1, qa, z4, 0, 0, 0);
    const int base = m + 287 - quad * 4 - gc;  // dwt idx for rr=0 (p0)
    float p0[4], p1[4];
#pragma unroll
    for (int rr = 0; rr < 4; ++rr) {
      const int g0 = gc + quad * 4 + rr;
      const int g1 = g0 + 16;
      p0[rr] = (g0 < H && g0 != m)
                   ? EXP2F(E0[rr] * dwt[base - rr]) : 0.0f;
      p1[rr] = (g1 < H && g1 != m)
                   ? EXP2F(E1[rr] * dwt[base - 16 - rr]) : 0.0f;
      Sacc += p0[rr] + p1[rr];
    }
    const short8 pa = pack_p(p0, p1);
#pragma unroll
    for (int ct = 0; ct < 4; ++ct)
      acc[ct] = __builtin_amdgcn_mfma_f32_16x16x32_bf16(pa, vb[ct], acc[ct], 0, 0, 0);
  }

  {
    float s = Sacc;
    s += __shfl_xor(s, 16);
    s += __shfl_xor(s, 32);
    if (lane < 16 && m < H) Sht[colbase + m] = s;
  }

  __syncthreads();
  unsigned short* ob = vbs;  // [c][288] stride VSH
#pragma unroll
  for (int ct = 0; ct < 4; ++ct)
#pragma unroll
    for (int rr = 0; rr < 4; ++rr)
      ob[(ct * 16 + l15) * VSH + m0 + quad * 4 + rr] = f2bf(acc[ct][rr]);
  __syncthreads();
  unsigned short* og = oht + ((size_t)b * W + w) * C * H;
  const int mlo = z ? 144 : 0;
  const int nu = z ? 63 : 72;  // u32 per c-row: z=0 rows 0-143, z=1 rows 144-269
  for (int idx = tid; idx < 64 * nu; idx += 576) {
    const int c = idx / nu, i = idx - c * nu;
    *(unsigned int*)(og + (size_t)c * H + mlo + 2 * i) =
        *(const unsigned int*)(ob + c * VSH + mlo + 2 * i);
  }
}

// ---------------------------------------------------------------------------
// K3b: invZ[b][h][w] = 1/(Sh+Sw), computed ONCE instead of redundantly per
// c-block in k_combine (64x).
// ---------------------------------------------------------------------------
__global__ __launch_bounds__(256)
void k_invz(const float* __restrict__ Sht, const float* __restrict__ Sw,
            float* __restrict__ invZ) {
  const int i = blockIdx.x * 256 + threadIdx.x;
  if (i >= B * HW) return;
  const int b = i / HW;
  const int r = i - b * HW;
  const int h = r / W;
  const int w = r - h * W;
  const float z = Sht[((size_t)b * W + w) * H + h] + Sw[i];
  invZ[i] = __builtin_amdgcn_rcpf(z);
}

// ---------------------------------------------------------------------------
// K4: out = gamma*(U_h + U_w)*invZ + x, LDS tile transpose for oht.
// ---------------------------------------------------------------------------
__global__ __launch_bounds__(256)
void k_combine(const unsigned short* __restrict__ oht,
               const unsigned short* __restrict__ ow,
               const float* __restrict__ izp,
               const float* __restrict__ x,
               const float* __restrict__ gp,
               float* __restrict__ out) {
  __shared__ float tile[32][33];
  const int b = blockIdx.z >> 6, c = blockIdx.z & 63;
  const int w0 = blockIdx.x * 32, h0 = blockIdx.y * 32;
  const int tx = threadIdx.x, ty = threadIdx.y;  // (32, 8)
#pragma unroll
  for (int i = 0; i < 4; ++i) {
    const int wl = ty + i * 8;
    const int hh = h0 + tx;
    float val = 0.0f;
    if (hh < H) val = bits2f(oht[(((size_t)b * W + (w0 + wl)) * C + c) * H + hh]);
    tile[wl][tx] = val;
  }
  __syncthreads();
  const float gamma = *gp;
#pragma unroll
  for (int i = 0; i < 4; ++i) {
    const int hl = ty + i * 8;
    const int hh = h0 + hl;
    if (hh < H) {
      const int ww = w0 + tx;
      const float uh = tile[tx][hl];
      const float uw = bits2f(ow[(((size_t)b * H + hh) * C + c) * W + ww]);
      const size_t si = ((size_t)b * H + hh) * W + ww;
      const float invZ = izp[si];
      const size_t xi = ((size_t)b * C + c) * HW + (size_t)hh * W + ww;
      out[xi] = fmaf(gamma * invZ, uh + uw, x[xi]);
    }
  }
}

}  // namespace

extern "C" void kernel_launch(void* const* d_in, const int* in_sizes, int n_in,
                              void* d_out, int out_size, void* d_ws, size_t ws_size,
                              hipStream_t stream) {
  (void)in_sizes; (void)n_in; (void)out_size; (void)ws_size;
  const float* x  = (const float*)d_in[0];
  const float* Wq = (const float*)d_in[1];
  const float* bq = (const float*)d_in[2];
  const float* Wk = (const float*)d_in[3];
  const float* bk = (const float*)d_in[4];
  const float* Wv = (const float*)d_in[5];
  const float* bv = (const float*)d_in[6];
  const float* gp = (const float*)d_in[7];
  float* out = (float*)d_out;

  char* p = (char*)d_ws;
  auto take = [&](size_t bytes) -> void* {
    char* r = p;
    p += (bytes + 255) & ~(size_t)255;
    return (void*)r;
  };
  unsigned short* qwp = (unsigned short*)take(sizeof(unsigned short) * (size_t)B * HW * 8);
  unsigned short* kwp = (unsigned short*)take(sizeof(unsigned short) * (size_t)B * HW * 8);
  unsigned short* qhp = (unsigned short*)take(sizeof(unsigned short) * (size_t)B * HW * 8);
  unsigned short* khp = (unsigned short*)take(sizeof(unsigned short) * (size_t)B * HW * 8);
  unsigned short* v   = (unsigned short*)take(sizeof(unsigned short) * (size_t)B * C * HW);
  unsigned short* vt  = (unsigned short*)take(sizeof(unsigned short) * (size_t)B * C * HW);
  unsigned short* oht = (unsigned short*)take(sizeof(unsigned short) * (size_t)B * C * HW);
  unsigned short* owb = (unsigned short*)take(sizeof(unsigned short) * (size_t)B * C * HW);
  float* Sht = (float*)take(sizeof(float) * (size_t)B * HW);
  float* Sw  = (float*)take(sizeof(float) * (size_t)B * HW);
  float* izb = (float*)take(sizeof(float) * (size_t)B * HW);

  hipLaunchKernelGGL(k_qkv, dim3((B * HW / 2 + 255) / 256), dim3(256), 0, stream,
                     x, Wq, bq, Wk, bk, Wv, bv, qwp, kwp, qhp, khp, v, vt);
  hipLaunchKernelGGL(k_outh, dim3(2 * W, B), dim3(576), 0, stream,
                     qhp, khp, vt, oht, Sht);
  hipLaunchKernelGGL(k_outw, dim3(2 * H, B), dim3(512), 0, stream,
                     qwp, kwp, v, owb, Sw);
  hipLaunchKernelGGL(k_invz, dim3((B * HW + 255) / 256), dim3(256), 0, stream,
                     Sht, Sw, izb);
  hipLaunchKernelGGL(k_combine, dim3(W / 32, (H + 31) / 32, B * C), dim3(32, 8), 0, stream,
                     oht, owb, izb, x, gp, out);
}